// Round 1
// baseline (206.187 us; speedup 1.0000x reference)
//
#include <hip/hip_runtime.h>
#include <math.h>

#define EPSF 1e-8f
#define LAMBDA_C 0.5f

constexpr int Bb = 8;
constexpr int Nn = 32768;
constexpr int Kk = 64;
constexpr int Dd = 64;

// Precompute per (b,k): ss2 = sum_{d=1..63} slots[b,k,d]^2  and  rh = 1/(h+eps).
__global__ void precomp_kernel(const float* __restrict__ slots,
                               const float* __restrict__ horizons,
                               float* __restrict__ pre) {
    int i = blockIdx.x * blockDim.x + threadIdx.x;
    if (i >= Bb * Kk) return;
    const float* srow = slots + (size_t)i * Dd;
    float s2 = 0.f;
    #pragma unroll
    for (int d = 1; d < Dd; ++d) s2 = fmaf(srow[d], srow[d], s2);
    pre[i] = s2;
    pre[Bb * Kk + i] = 1.0f / (horizons[i] + EPSF);
}

// One thread per (b,n). Slot operands are block-uniform -> s_load into SGPRs,
// so the 64x63 FMA stream reads its second operand from SGPRs (no LDS/VMEM BW).
__global__ __launch_bounds__(128) void attn_kernel(
    const float* __restrict__ features,
    const float* __restrict__ slots,
    const float* __restrict__ pre,
    float* __restrict__ out)
{
    // Thread-private logit storage (avoids dynamic-index scratch spill).
    // Layout lg[k*128+tid]: lanes hit consecutive banks, 2 lanes/bank = free.
    __shared__ float lg[Kk * 128];   // 32 KiB -> ~5 blocks/CU by LDS
    const int tid = threadIdx.x;
    const int b = blockIdx.x >> 8;               // 256 blocks per batch
    const int n = ((blockIdx.x & 255) << 7) + tid;

    const float4* frow = (const float4*)(features + ((size_t)b * Nn + n) * Dd);
    float fr[Dd];
    #pragma unroll
    for (int i = 0; i < Dd / 4; ++i) {
        float4 v = frow[i];
        fr[4*i+0] = v.x; fr[4*i+1] = v.y; fr[4*i+2] = v.z; fr[4*i+3] = v.w;
    }
    const float ft = fr[0];
    float fs2 = 0.f;
    #pragma unroll
    for (int d = 1; d < Dd; ++d) fs2 = fmaf(fr[d], fr[d], fs2);

    const float* sb   = slots + (size_t)b * Kk * Dd;
    const float* ss2p = pre + b * Kk;
    const float* rhp  = pre + Bb * Kk + b * Kk;

    #pragma unroll 1
    for (int k = 0; k < Kk; ++k) {
        const float4* srow = (const float4*)(sb + k * Dd);
        // Full 64-dim dot with 4 independent chains; subtract time lane after.
        float a0 = 0.f, a1 = 0.f, a2 = 0.f, a3 = 0.f;
        #pragma unroll
        for (int i = 0; i < Dd / 4; ++i) {
            float4 s = srow[i];
            a0 = fmaf(fr[4*i+0], s.x, a0);
            a1 = fmaf(fr[4*i+1], s.y, a1);
            a2 = fmaf(fr[4*i+2], s.z, a2);
            a3 = fmaf(fr[4*i+3], s.w, a3);
        }
        const float st = sb[k * Dd];
        float cross = ((a0 + a1) + (a2 + a3)) - ft * st;   // sum over d=1..63
        float dt  = ft - st;
        float t   = fs2 + ss2p[k];
        float dx2 = fmaf(-2.f, cross, t);
        dx2 = fmaxf(dx2, 0.f);
        float interval = fmaf(dt, dt, -dx2);
        float adist = sqrtf(fabsf(interval) + EPSF);       // |dist|; sign irrelevant
        float cone  = (fabsf(dt) - sqrtf(dx2 + EPSF)) * rhp[k];
        // tanh(x) = 1 - 2/(e^{2x}+1): saturates cleanly at +/-inf, no NaN.
        float e  = __expf(2.f * cone);
        float th = 1.f - 2.f * __builtin_amdgcn_rcpf(e + 1.f);
        lg[k * 128 + tid] = fmaf(LAMBDA_C, th, -adist);
    }

    // Softmax over k (thread-private column; no barrier needed).
    float m = lg[tid];
    #pragma unroll 1
    for (int k = 1; k < Kk; ++k) m = fmaxf(m, lg[k * 128 + tid]);
    float ssum = 0.f;
    #pragma unroll 1
    for (int k = 0; k < Kk; ++k) ssum += __expf(lg[k * 128 + tid] - m);
    const float inv = 1.0f / ssum;

    float* ob = out + ((size_t)b * Kk) * Nn + n;
    #pragma unroll 1
    for (int k = 0; k < Kk; ++k)
        ob[(size_t)k * Nn] = __expf(lg[k * 128 + tid] - m) * inv;
}

extern "C" void kernel_launch(void* const* d_in, const int* in_sizes, int n_in,
                              void* d_out, int out_size, void* d_ws, size_t ws_size,
                              hipStream_t stream) {
    const float* features = (const float*)d_in[0];
    const float* slots    = (const float*)d_in[1];
    const float* horizons = (const float*)d_in[2];
    float* out = (float*)d_out;
    float* pre = (float*)d_ws;   // [0, B*K): ss2, [B*K, 2*B*K): 1/(h+eps)

    hipLaunchKernelGGL(precomp_kernel, dim3(2), dim3(256), 0, stream,
                       slots, horizons, pre);
    hipLaunchKernelGGL(attn_kernel, dim3((Bb * Nn) / 128), dim3(128), 0, stream,
                       features, slots, pre, out);
}